// Round 7
// baseline (113.790 us; speedup 1.0000x reference)
//
#include <hip/hip_runtime.h>
#include <hip/hip_bf16.h>

typedef __bf16 bf16x8 __attribute__((ext_vector_type(8)));
typedef float f32x4 __attribute__((ext_vector_type(4)));

#define GN    1024
#define BATCH 64
#define CIN   256
#define COUT  256
#define NG    4                      // g's per persistent block
#define A_ELEMS (BATCH * CIN)        // 16384 ushorts = 32 KB
#define WSLICE  8192                 // per wave, per buffer: 64 o-rows x 32 k x 4B
#define NWBUF   3                    // W ring depth

#define G_AS __attribute__((address_space(1)))
#define L_AS __attribute__((address_space(3)))

static __device__ __forceinline__ void gload16(const void* g, void* l) {
  __builtin_amdgcn_global_load_lds((const G_AS void*)g, (L_AS void*)l, 16, 0, 0);
}

static __device__ __forceinline__ void vmwait(int n) {
  if (n == 0)       asm volatile("s_waitcnt vmcnt(0)"  ::: "memory");
  else if (n == 8)  asm volatile("s_waitcnt vmcnt(8)"  ::: "memory");
  else if (n == 16) asm volatile("s_waitcnt vmcnt(16)" ::: "memory");
  else if (n == 24) asm volatile("s_waitcnt vmcnt(24)" ::: "memory");
  else if (n == 32) asm volatile("s_waitcnt vmcnt(32)" ::: "memory");
  else              asm volatile("s_waitcnt vmcnt(40)" ::: "memory");
}

static __device__ __forceinline__ ushort f2bf(float f) {
  __hip_bfloat16 h = __float2bfloat16(f);
  return *reinterpret_cast<ushort*>(&h);
}
static __device__ __forceinline__ float bf2f(ushort u) {
  uint v = (uint)u << 16;
  return *reinterpret_cast<float*>(&v);
}

// ---------------------------------------------------------------------------
// Kernel 1: transpose + convert  x[b][i][g] (f32) -> xT[b][g][i^((b&7)<<3)] (bf16)
// xT stored PRE-SWIZZLED in i so k2 can DMA it linearly (rule 21).
// ---------------------------------------------------------------------------
__global__ __launch_bounds__(256) void k_transpose_convert(
    const float* __restrict__ x, ushort* __restrict__ xT)
{
  __shared__ float tile[64][65];
  const int g0 = blockIdx.x * 64;
  const int i0 = blockIdx.y * 64;
  const int b  = blockIdx.z;
  const int t  = threadIdx.x;
  const int a  = t & 15;
  const int r  = t >> 4;
  const int key = (b & 7) << 3;

  const float* xb = x + (size_t)b * CIN * GN;
#pragma unroll
  for (int p = 0; p < 4; ++p) {
    int ii = p * 16 + r;
    float4 v = *reinterpret_cast<const float4*>(
        &xb[(size_t)(i0 + ii) * GN + g0 + a * 4]);
    tile[ii][a * 4 + 0] = v.x;
    tile[ii][a * 4 + 1] = v.y;
    tile[ii][a * 4 + 2] = v.z;
    tile[ii][a * 4 + 3] = v.w;
  }
  __syncthreads();

  ushort* xTb = xT + (size_t)b * GN * CIN;
#pragma unroll
  for (int p = 0; p < 4; ++p) {
    int gg = p * 16 + r;
    ushort4 u;
    u.x = f2bf(tile[a * 4 + 0][gg]);
    u.y = f2bf(tile[a * 4 + 1][gg]);
    u.z = f2bf(tile[a * 4 + 2][gg]);
    u.w = f2bf(tile[a * 4 + 3][gg]);
    int isw = (i0 + a * 4) ^ key;
    *reinterpret_cast<ushort4*>(&xTb[(size_t)(g0 + gg) * CIN + isw]) = u;
  }
}

// ---------------------------------------------------------------------------
// Kernel 2: PERSISTENT per-group GEMM. grid = GN/NG = 256 blocks (1/CU).
// W: per-wave RING-3 buffers (8 KB each), one continuous DMA stream across
//    all NG g's: stage s+3 issued at step s, consumed at step s+3 (~3 ks
//    of latency headroom). A: 2x32 KB dbuf, A(g+1) staged at ks=4.
// outT layout [g][o][b] so the epilogue is 16 ushort4 stores (exact ledger).
// vmcnt ledger (16 stores/g, A' at ks4 after that step's W-issue):
//   gi=0:   {16,16,16,16,16,16,24,24}
//   gi=1,2: {32,32,32,16,16,16,24,24}
//   gi=3:   {32,32,32,16,16,16, 8, 0}
//   g-boundary (gi<3): vmcnt(40) [retires A'+older], s_barrier.
//   prologue: bias16+A8+W0,1,2 -> vmcnt(24), s_barrier.
// ---------------------------------------------------------------------------
__global__ __launch_bounds__(256) void k_group_gemm(
    const ushort* __restrict__ xT, const float* __restrict__ W,
    const float* __restrict__ bias, float* __restrict__ out,
    ushort* __restrict__ outT, int use_ws)
{
  __shared__ __align__(16) unsigned char lds[2 * A_ELEMS * 2 + 4 * NWBUF * WSLICE]; // 160 KB
  ushort* lA        = (ushort*)lds;
  unsigned char* lW = lds + 2 * A_ELEMS * 2;

  const int tid  = threadIdx.x;
  const int wave = tid >> 6;
  const int lane = tid & 63;
  const int g_base = blockIdx.x * NG;

  const int arow = lane & 15;
  const int q    = lane >> 4;        // 0..3
  const int colk = q * 32;
  const int kq   = q << 3;
  const int oc   = 64 * wave + arow;

  unsigned char* lWw = lW + wave * (NWBUF * WSLICE);
  const int swz_src = ((lane & 7) ^ (lane >> 3)) << 4;
  const int wrow    = lane >> 3;

  auto stage_a = [&](int gg, int ab) {
    ushort* base = lA + ab * A_ELEMS;
#pragma unroll
    for (int j = 0; j < 8; ++j) {
      int b = 16 * wave + 2 * j + (lane >> 5);
      const ushort* gsrc = xT + ((size_t)b * GN + gg) * CIN + (lane & 31) * 8;
      gload16(gsrc, base + (16 * wave + 2 * j) * CIN);
    }
  };
  auto stage_w = [&](int gg, int ksl, int buf) {
    unsigned char* ldb = lWw + buf * WSLICE;
    const unsigned char* gb = (const unsigned char*)(W + ((size_t)gg * COUT + 64 * wave) * CIN)
                              + (size_t)ksl * 128 + swz_src;
#pragma unroll
    for (int j = 0; j < 8; ++j) {
      gload16(gb + (size_t)(8 * j + wrow) * (CIN * 4), ldb + j * 1024);
    }
  };

  const int NTAB[4][8] = {{16,16,16,16,16,16,24,24},
                          {32,32,32,16,16,16,24,24},
                          {32,32,32,16,16,16,24,24},
                          {32,32,32,16,16,16, 8, 0}};

  // ---- prologue ----
  float bvv[NG][4];
#pragma unroll
  for (int gi = 0; gi < NG; ++gi)
#pragma unroll
    for (int n = 0; n < 4; ++n)
      bvv[gi][n] = bias[(g_base + gi) * COUT + oc + n * 16];
  __builtin_amdgcn_sched_barrier(0);

  stage_a(g_base, 0);
  __builtin_amdgcn_sched_barrier(0);
  stage_w(g_base, 0, 0);
  stage_w(g_base, 1, 1);
  stage_w(g_base, 2, 2);
  __builtin_amdgcn_sched_barrier(0);
  vmwait(24);                       // retire bias + A, keep W0..W2
  __builtin_amdgcn_sched_barrier(0);
  __builtin_amdgcn_s_barrier();

#pragma unroll
  for (int gi = 0; gi < NG; ++gi) {
    const int g = g_base + gi;
    const ushort* lAc = lA + (gi & 1) * A_ELEMS;

    f32x4 acc[4][4];
#pragma unroll
    for (int m = 0; m < 4; ++m)
#pragma unroll
      for (int n = 0; n < 4; ++n)
        acc[m][n] = {0.f, 0.f, 0.f, 0.f};

#pragma unroll
    for (int ks = 0; ks < 8; ++ks) {
      vmwait(NTAB[gi][ks]);
      __builtin_amdgcn_sched_barrier(0);

      const int s = gi * 8 + ks;
      unsigned char* wb = lWw + (s % 3) * WSLICE;
      const int key = (arow & 7) << 4;

      float4 f[4][2];
#pragma unroll
      for (int n = 0; n < 4; ++n) {
        int r = n * 16 + arow;
        f[n][0] = *reinterpret_cast<const float4*>(wb + r * 128 + (colk ^ key));
        f[n][1] = *reinterpret_cast<const float4*>(wb + r * 128 + ((colk + 16) ^ key));
      }
      bf16x8 afr[4];
      const int i0 = ks * 32 + kq;
#pragma unroll
      for (int m = 0; m < 4; ++m) {
        int row = m * 16 + arow;
        afr[m] = *reinterpret_cast<const bf16x8*>(
            &lAc[row * CIN + (i0 ^ ((row & 7) << 3))]);
      }

      asm volatile("s_waitcnt lgkmcnt(0)" ::: "memory");
      __builtin_amdgcn_sched_barrier(0);
      if (s + 3 < NG * 8) {
        const int s2 = s + 3;
        stage_w(g_base + (s2 >> 3), s2 & 7, s2 % 3);
      }
      if (ks == 4 && gi < NG - 1) stage_a(g + 1, (gi & 1) ^ 1);
      __builtin_amdgcn_sched_barrier(0);

      bf16x8 bfr[4];
#pragma unroll
      for (int n = 0; n < 4; ++n) {
        bfr[n][0] = (__bf16)f[n][0].x; bfr[n][1] = (__bf16)f[n][0].y;
        bfr[n][2] = (__bf16)f[n][0].z; bfr[n][3] = (__bf16)f[n][0].w;
        bfr[n][4] = (__bf16)f[n][1].x; bfr[n][5] = (__bf16)f[n][1].y;
        bfr[n][6] = (__bf16)f[n][1].z; bfr[n][7] = (__bf16)f[n][1].w;
      }

      __builtin_amdgcn_s_setprio(1);
#pragma unroll
      for (int m = 0; m < 4; ++m)
#pragma unroll
        for (int n = 0; n < 4; ++n)
          acc[m][n] = __builtin_amdgcn_mfma_f32_16x16x32_bf16(
              afr[m], bfr[n], acc[m][n], 0, 0, 0);
      __builtin_amdgcn_s_setprio(0);
    }

    // ---- epilogue for g: 16 ushort4 stores to outT[g][o][b] ----
    if (use_ws) {
#pragma unroll
      for (int m = 0; m < 4; ++m) {
#pragma unroll
        for (int n = 0; n < 4; ++n) {
          int o = oc + n * 16;
          ushort4 u;
          u.x = f2bf(acc[m][n][0] + bvv[gi][n]);
          u.y = f2bf(acc[m][n][1] + bvv[gi][n]);
          u.z = f2bf(acc[m][n][2] + bvv[gi][n]);
          u.w = f2bf(acc[m][n][3] + bvv[gi][n]);
          *reinterpret_cast<ushort4*>(
              &outT[((size_t)g * COUT + o) * BATCH + m * 16 + 4 * q]) = u;
        }
      }
    } else {
#pragma unroll
      for (int m = 0; m < 4; ++m) {
#pragma unroll
        for (int n = 0; n < 4; ++n) {
          int o = oc + n * 16;
#pragma unroll
          for (int j = 0; j < 4; ++j) {
            int b = m * 16 + 4 * q + j;
            out[((size_t)b * COUT + o) * GN + g] = acc[m][n][j] + bvv[gi][n];
          }
        }
      }
    }
    __builtin_amdgcn_sched_barrier(0);

    if (gi < NG - 1) {
      vmwait(40);                   // retire A' (+older); keep W-stages+stores
      __builtin_amdgcn_sched_barrier(0);
      __builtin_amdgcn_s_barrier();
    }
  }
}

// ---------------------------------------------------------------------------
// Kernel 3: transpose  outT[g][o][b] (bf16) -> out[b][o][g] (f32)
// block = (g-tile 64) x (one o); tile [g][b].
// ---------------------------------------------------------------------------
__global__ __launch_bounds__(256) void k_transpose_out(
    const ushort* __restrict__ outT, float* __restrict__ out)
{
  __shared__ float tile[64][65];  // [g][b]
  const int g0 = blockIdx.x * 64;
  const int o  = blockIdx.y;
  const int t  = threadIdx.x;

  // read: 64 g-rows x 128B, 8 lanes x int4 per row
  {
    const int a  = t & 7;
#pragma unroll
    for (int p = 0; p < 2; ++p) {
      int gl = p * 32 + (t >> 3);
      int4 raw = *reinterpret_cast<const int4*>(
          &outT[((size_t)(g0 + gl) * COUT + o) * BATCH + a * 8]);
      const ushort* us = reinterpret_cast<const ushort*>(&raw);
#pragma unroll
      for (int e = 0; e < 8; ++e) tile[gl][a * 8 + e] = bf2f(us[e]);
    }
  }
  __syncthreads();

  // write: 64 b-rows, float4 of 4 consecutive g per lane
  {
    const int a2 = t & 15;
#pragma unroll
    for (int p = 0; p < 4; ++p) {
      int bl = p * 16 + (t >> 4);
      float4 v;
      v.x = tile[4 * a2 + 0][bl];
      v.y = tile[4 * a2 + 1][bl];
      v.z = tile[4 * a2 + 2][bl];
      v.w = tile[4 * a2 + 3][bl];
      *reinterpret_cast<float4*>(
          &out[((size_t)bl * COUT + o) * GN + g0 + 4 * a2]) = v;
    }
  }
}

// ---------------------------------------------------------------------------
extern "C" void kernel_launch(void* const* d_in, const int* in_sizes, int n_in,
                              void* d_out, int out_size, void* d_ws, size_t ws_size,
                              hipStream_t stream) {
  const float* x  = (const float*)d_in[0];
  const float* W  = (const float*)d_in[1];
  const float* bs = (const float*)d_in[2];
  float* out      = (float*)d_out;

  const size_t xT_elems = (size_t)BATCH * GN * CIN;
  const size_t oT_elems = (size_t)GN * COUT * BATCH;
  const bool use_ws = ws_size >= (xT_elems + oT_elems) * sizeof(ushort);

  ushort* xT   = (ushort*)d_ws;
  ushort* outT = xT + xT_elems;

  dim3 grid1(GN / 64, CIN / 64, BATCH);
  k_transpose_convert<<<grid1, 256, 0, stream>>>(x, xT);
  k_group_gemm<<<GN / NG, 256, 0, stream>>>(xT, W, bs, out,
                                            use_ws ? outT : nullptr,
                                            use_ws ? 1 : 0);
  if (use_ws) {
    dim3 grid3(GN / 64, COUT);
    k_transpose_out<<<grid3, 256, 0, stream>>>(outT, out);
  }
}

// Round 8
// 112.830 us; speedup vs baseline: 1.0085x; 1.0085x over previous
//
#include <hip/hip_runtime.h>
#include <hip/hip_bf16.h>

typedef __bf16 bf16x8 __attribute__((ext_vector_type(8)));
typedef float f32x4 __attribute__((ext_vector_type(4)));

#define GN    1024
#define BATCH 64
#define CIN   256
#define COUT  256
#define NG    4
#define A_BYTES (BATCH * CIN * 2)   // 32 KB, single buffer
#define WCHUNK  16384               // 16 contiguous o-rows x 1 KB (full K)

#define G_AS __attribute__((address_space(1)))
#define L_AS __attribute__((address_space(3)))

static __device__ __forceinline__ void gload16(const void* g, void* l) {
  __builtin_amdgcn_global_load_lds((const G_AS void*)g, (L_AS void*)l, 16, 0, 0);
}

static __device__ __forceinline__ ushort f2bf(float f) {
  __hip_bfloat16 h = __float2bfloat16(f);
  return *reinterpret_cast<ushort*>(&h);
}
static __device__ __forceinline__ float bf2f(ushort u) {
  uint v = (uint)u << 16;
  return *reinterpret_cast<float*>(&v);
}

// ---------------------------------------------------------------------------
// Kernel 1: transpose + convert  x[b][i][g] (f32) -> xT[b][g][i^((b&7)<<3)] (bf16)
// xT stored PRE-SWIZZLED in i so k2 can DMA it linearly (rule 21).
// ---------------------------------------------------------------------------
__global__ __launch_bounds__(256) void k_transpose_convert(
    const float* __restrict__ x, ushort* __restrict__ xT)
{
  __shared__ float tile[64][65];
  const int g0 = blockIdx.x * 64;
  const int i0 = blockIdx.y * 64;
  const int b  = blockIdx.z;
  const int t  = threadIdx.x;
  const int a  = t & 15;
  const int r  = t >> 4;
  const int key = (b & 7) << 3;

  const float* xb = x + (size_t)b * CIN * GN;
#pragma unroll
  for (int p = 0; p < 4; ++p) {
    int ii = p * 16 + r;
    float4 v = *reinterpret_cast<const float4*>(
        &xb[(size_t)(i0 + ii) * GN + g0 + a * 4]);
    tile[ii][a * 4 + 0] = v.x;
    tile[ii][a * 4 + 1] = v.y;
    tile[ii][a * 4 + 2] = v.z;
    tile[ii][a * 4 + 3] = v.w;
  }
  __syncthreads();

  ushort* xTb = xT + (size_t)b * GN * CIN;
#pragma unroll
  for (int p = 0; p < 4; ++p) {
    int gg = p * 16 + r;
    ushort4 u;
    u.x = f2bf(tile[a * 4 + 0][gg]);
    u.y = f2bf(tile[a * 4 + 1][gg]);
    u.z = f2bf(tile[a * 4 + 2][gg]);
    u.w = f2bf(tile[a * 4 + 3][gg]);
    int isw = (i0 + a * 4) ^ key;
    *reinterpret_cast<ushort4*>(&xTb[(size_t)(g0 + gg) * CIN + isw]) = u;
  }
}

// ---------------------------------------------------------------------------
// Kernel 2: persistent per-group GEMM with SEQUENTIAL W streaming.
// grid = GN/NG = 256 blocks (1/CU), 4 waves; wave owns o in [64w, 64w+64)
// = 64 KB of W per g, CONTIGUOUS. Staged as 4 chunks of 16 complete o-rows
// (16 KB contiguous), per-wave ring-2. Chunk c == MFMA n-tile c.
// DMA source lane-permuted within each 1 KB row: (lane ^ (j&7))<<4, undone
// on the LDS read side (bank spread, rule 21).
// vmcnt ledger (per wave; chunk=16 ops, A=8, stores=16, bias=16):
//   prologue: bias,A0,C0,C1 -> vmcnt(16); barrier
//   s=0: none; s=1,2,3: 16
//   g-end (s=3,7,11): lgkm0, MFMA, barrier, A', C(s+2), stores
//   s=4,8,12: 32 (retires C_old+A' exactly); s=5,9,13: 32; s=6,10,14: 16
//   s=15: 0
// ---------------------------------------------------------------------------
__global__ __launch_bounds__(256) void k_group_gemm(
    const ushort* __restrict__ xT, const float* __restrict__ W,
    const float* __restrict__ bias, float* __restrict__ out,
    ushort* __restrict__ outT, int use_ws)
{
  __shared__ __align__(16) unsigned char lds[A_BYTES + 4 * 2 * WCHUNK]; // 160 KB
  ushort* lA        = (ushort*)lds;
  unsigned char* lW = lds + A_BYTES;

  const int tid  = threadIdx.x;
  const int wave = tid >> 6;
  const int lane = tid & 63;
  const int g_base = blockIdx.x * NG;

  const int arow = lane & 15;
  const int q    = lane >> 4;
  const int oc   = 64 * wave + arow;

  unsigned char* lWw = lW + wave * (2 * WCHUNK);

  auto stage_a = [&](int gg) {
#pragma unroll
    for (int j = 0; j < 8; ++j) {
      int b = 16 * wave + 2 * j + (lane >> 5);
      const ushort* gsrc = xT + ((size_t)b * GN + gg) * CIN + (lane & 31) * 8;
      gload16(gsrc, lA + (16 * wave + 2 * j) * CIN);
    }
  };
  // stage global chunk step sg (= gi*4+c): 16 KB contiguous, row-permuted src
  auto stage_wc = [&](int sg) {
    const int gg = g_base + (sg >> 2);
    const int c  = sg & 3;
    unsigned char* ldb = lWw + (sg & 1) * WCHUNK;
    const unsigned char* gb = (const unsigned char*)W
        + ((size_t)gg * COUT + 64 * wave + 16 * c) * (CIN * 4);
#pragma unroll
    for (int j = 0; j < 16; ++j) {
      gload16(gb + (size_t)j * (CIN * 4) + ((lane ^ (j & 7)) << 4),
              ldb + j * 1024);
    }
  };

  // ---- prologue ----
  float bvv[NG][4];
#pragma unroll
  for (int gi = 0; gi < NG; ++gi)
#pragma unroll
    for (int n = 0; n < 4; ++n)
      bvv[gi][n] = bias[(g_base + gi) * COUT + oc + n * 16];
  __builtin_amdgcn_sched_barrier(0);

  stage_a(g_base);
  __builtin_amdgcn_sched_barrier(0);
  stage_wc(0);
  stage_wc(1);
  __builtin_amdgcn_sched_barrier(0);
  asm volatile("s_waitcnt vmcnt(16)" ::: "memory");  // retire bias+A0+C0
  __builtin_amdgcn_sched_barrier(0);
  __builtin_amdgcn_s_barrier();

  const int NTAB[16] = {-1, 16, 16, 16, 32, 32, 16, 16,
                        32, 32, 16, 16, 32, 32, 16, 0};

#pragma unroll
  for (int gi = 0; gi < NG; ++gi) {
    const int g = g_base + gi;

    f32x4 acc[4][4];  // [m][chunk]
#pragma unroll
    for (int m = 0; m < 4; ++m)
#pragma unroll
      for (int n = 0; n < 4; ++n)
        acc[m][n] = {0.f, 0.f, 0.f, 0.f};

#pragma unroll
    for (int c = 0; c < 4; ++c) {
      const int s = gi * 4 + c;
      const int nt = NTAB[s];
      if (nt == 0)       { asm volatile("s_waitcnt vmcnt(0)"  ::: "memory"); }
      else if (nt == 16) { asm volatile("s_waitcnt vmcnt(16)" ::: "memory"); }
      else if (nt == 32) { asm volatile("s_waitcnt vmcnt(32)" ::: "memory"); }
      __builtin_amdgcn_sched_barrier(0);

      unsigned char* wb = lWw + (s & 1) * WCHUNK;
      const int key = (arow & 7) << 4;
      const int rb  = arow * 1024;

#pragma unroll
      for (int ks = 0; ks < 8; ++ks) {
        float4 f0 = *reinterpret_cast<const float4*>(
            wb + rb + ks * 128 + ((q * 32) ^ key));
        float4 f1 = *reinterpret_cast<const float4*>(
            wb + rb + ks * 128 + ((q * 32 + 16) ^ key));

        bf16x8 afr[4];
        const int i0 = ks * 32 + q * 8;
#pragma unroll
        for (int m = 0; m < 4; ++m) {
          int row = m * 16 + arow;
          afr[m] = *reinterpret_cast<const bf16x8*>(
              &lA[row * CIN + (i0 ^ ((row & 7) << 3))]);
        }

        bf16x8 bfr;
        bfr[0] = (__bf16)f0.x; bfr[1] = (__bf16)f0.y;
        bfr[2] = (__bf16)f0.z; bfr[3] = (__bf16)f0.w;
        bfr[4] = (__bf16)f1.x; bfr[5] = (__bf16)f1.y;
        bfr[6] = (__bf16)f1.z; bfr[7] = (__bf16)f1.w;

        __builtin_amdgcn_s_setprio(1);
#pragma unroll
        for (int m = 0; m < 4; ++m)
          acc[m][c] = __builtin_amdgcn_mfma_f32_16x16x32_bf16(
              afr[m], bfr, acc[m][c], 0, 0, 0);
        __builtin_amdgcn_s_setprio(0);
      }

      // chunk end: retire this slot's ds_reads, then refill it
      asm volatile("s_waitcnt lgkmcnt(0)" ::: "memory");
      __builtin_amdgcn_sched_barrier(0);
      if (c < 3) {
        if (s + 2 < 4 * NG) stage_wc(s + 2);
        __builtin_amdgcn_sched_barrier(0);
      }
    }

    // ---- end of g: barrier (lA safe), A', next W chunk, stores ----
    __builtin_amdgcn_s_barrier();
    if (gi < NG - 1) stage_a(g + 1);
    {
      const int s = gi * 4 + 3;
      if (s + 2 < 4 * NG) stage_wc(s + 2);
    }
    __builtin_amdgcn_sched_barrier(0);

    if (use_ws) {
#pragma unroll
      for (int m = 0; m < 4; ++m) {
#pragma unroll
        for (int n = 0; n < 4; ++n) {
          int o = oc + n * 16;
          ushort4 u;
          u.x = f2bf(acc[m][n][0] + bvv[gi][n]);
          u.y = f2bf(acc[m][n][1] + bvv[gi][n]);
          u.z = f2bf(acc[m][n][2] + bvv[gi][n]);
          u.w = f2bf(acc[m][n][3] + bvv[gi][n]);
          *reinterpret_cast<ushort4*>(
              &outT[((size_t)g * COUT + o) * BATCH + m * 16 + 4 * q]) = u;
        }
      }
    } else {
#pragma unroll
      for (int m = 0; m < 4; ++m) {
#pragma unroll
        for (int n = 0; n < 4; ++n) {
          int o = oc + n * 16;
#pragma unroll
          for (int j = 0; j < 4; ++j) {
            int b = m * 16 + 4 * q + j;
            out[((size_t)b * COUT + o) * GN + g] = acc[m][n][j] + bvv[gi][n];
          }
        }
      }
    }
    __builtin_amdgcn_sched_barrier(0);
  }
}

// ---------------------------------------------------------------------------
// Kernel 3: transpose  outT[g][o][b] (bf16) -> out[b][o][g] (f32)
// ---------------------------------------------------------------------------
__global__ __launch_bounds__(256) void k_transpose_out(
    const ushort* __restrict__ outT, float* __restrict__ out)
{
  __shared__ float tile[64][65];  // [g][b]
  const int g0 = blockIdx.x * 64;
  const int o  = blockIdx.y;
  const int t  = threadIdx.x;

  {
    const int a = t & 7;
#pragma unroll
    for (int p = 0; p < 2; ++p) {
      int gl = p * 32 + (t >> 3);
      int4 raw = *reinterpret_cast<const int4*>(
          &outT[((size_t)(g0 + gl) * COUT + o) * BATCH + a * 8]);
      const ushort* us = reinterpret_cast<const ushort*>(&raw);
#pragma unroll
      for (int e = 0; e < 8; ++e) tile[gl][a * 8 + e] = bf2f(us[e]);
    }
  }
  __syncthreads();

  {
    const int a2 = t & 15;
#pragma unroll
    for (int p = 0; p < 4; ++p) {
      int bl = p * 16 + (t >> 4);
      float4 v;
      v.x = tile[4 * a2 + 0][bl];
      v.y = tile[4 * a2 + 1][bl];
      v.z = tile[4 * a2 + 2][bl];
      v.w = tile[4 * a2 + 3][bl];
      *reinterpret_cast<float4*>(
          &out[((size_t)bl * COUT + o) * GN + g0 + 4 * a2]) = v;
    }
  }
}

// ---------------------------------------------------------------------------
extern "C" void kernel_launch(void* const* d_in, const int* in_sizes, int n_in,
                              void* d_out, int out_size, void* d_ws, size_t ws_size,
                              hipStream_t stream) {
  const float* x  = (const float*)d_in[0];
  const float* W  = (const float*)d_in[1];
  const float* bs = (const float*)d_in[2];
  float* out      = (float*)d_out;

  const size_t xT_elems = (size_t)BATCH * GN * CIN;
  const size_t oT_elems = (size_t)GN * COUT * BATCH;
  const bool use_ws = ws_size >= (xT_elems + oT_elems) * sizeof(ushort);

  ushort* xT   = (ushort*)d_ws;
  ushort* outT = xT + xT_elems;

  dim3 grid1(GN / 64, CIN / 64, BATCH);
  k_transpose_convert<<<grid1, 256, 0, stream>>>(x, xT);
  k_group_gemm<<<GN / NG, 256, 0, stream>>>(xT, W, bs, out,
                                            use_ws ? outT : nullptr,
                                            use_ws ? 1 : 0);
  if (use_ws) {
    dim3 grid3(GN / 64, COUT);
    k_transpose_out<<<grid3, 256, 0, stream>>>(outT, out);
  }
}